// Round 1
// baseline (485.679 us; speedup 1.0000x reference)
//
#include <hip/hip_runtime.h>

typedef __attribute__((ext_vector_type(8))) short short8;
typedef __attribute__((ext_vector_type(4))) short short4v;
typedef __attribute__((ext_vector_type(4))) float floatx4;

__device__ __forceinline__ unsigned short f2bf(float f) {
    unsigned int u = __float_as_uint(f);
    u += 0x7FFFu + ((u >> 16) & 1u);   // round-to-nearest-even
    return (unsigned short)(u >> 16);
}

// Fused gather + bf16 GEMM (concat[131072,512] @ W[512,512]) + sigmoid gates +
// gated combine + row scatter.
// Block: 512 threads (8 waves), owns 64 occurrence rows (BM=64).
// Wave w computes cols d in [32w, 32w+32) for BOTH forget (n=d) and add
// (n=256+d) logits -> epilogue combine is wave-local.
__global__ __launch_bounds__(512)
void gate_gemm_kernel(const float* __restrict__ flat,   // [262144,256]
                      const float* __restrict__ syms,   // [20000,256]
                      const float* __restrict__ Wf,     // [256,512]
                      const float* __restrict__ bfb,    // [256]
                      const float* __restrict__ Wa,     // [256,512]
                      const float* __restrict__ bab,    // [256]
                      const int* __restrict__ expr_idx,
                      const int* __restrict__ token_idx,
                      const int* __restrict__ sym_idx,
                      float* __restrict__ out)          // [262144,256]
{
    __shared__ __align__(16) short A_lds[64][40];  // 64 rows x 32 k, +8 pad
    __shared__ int rowbuf[64];
    __shared__ int symbuf[64];

    const int tid  = threadIdx.x;
    const int occ0 = blockIdx.x * 64;

    if (tid < 64) {
        int occ = occ0 + tid;
        rowbuf[tid] = 64 * expr_idx[occ] + token_idx[occ];
        symbuf[tid] = sym_idx[occ];
    }
    __syncthreads();

    // staging role: thread t loads one float4 of row (t>>3), k-quad (t&7)
    const int sm  = tid >> 3;
    const int skq = tid & 7;
    const float* prow = flat + (long)rowbuf[sm] * 256;
    const float* urow = syms + (long)symbuf[sm] * 256;

    const int lane  = tid & 63;
    const int wv    = tid >> 6;   // 0..7
    const int l15   = lane & 15;
    const int lk    = lane >> 4;  // 0..3
    const int dbase = wv * 32;

    floatx4 acc[4][4];
    #pragma unroll
    for (int r = 0; r < 4; ++r)
        #pragma unroll
        for (int c = 0; c < 4; ++c)
            acc[r][c] = (floatx4){0.f, 0.f, 0.f, 0.f};

    for (int ks = 0; ks < 16; ++ks) {
        // ---- stage A tile (fp32 gather -> bf16 LDS) ----
        const int kg = ks * 32 + skq * 4;
        const float* src = (kg < 256) ? (prow + kg) : (urow + (kg - 256));
        floatx4 v = *(const floatx4*)src;
        short4v sv;
        sv[0] = (short)f2bf(v[0]); sv[1] = (short)f2bf(v[1]);
        sv[2] = (short)f2bf(v[2]); sv[3] = (short)f2bf(v[3]);
        *(short4v*)&A_lds[sm][skq * 4] = sv;
        __syncthreads();

        // ---- A fragments from LDS ----
        short8 af[4];
        #pragma unroll
        for (int r = 0; r < 4; ++r)
            af[r] = *(const short8*)&A_lds[r * 16 + l15][lk * 8];

        // ---- B fragments straight from global (L2-resident weights) ----
        #pragma unroll
        for (int c = 0; c < 4; ++c) {
            const float* wbase = (c < 2) ? Wf : Wa;
            const float* wp = wbase + (long)(dbase + (c & 1) * 16 + l15) * 512
                              + ks * 32 + lk * 8;
            floatx4 w0 = *(const floatx4*)wp;
            floatx4 w1 = *(const floatx4*)(wp + 4);
            short8 bfr;
            bfr[0] = (short)f2bf(w0[0]); bfr[1] = (short)f2bf(w0[1]);
            bfr[2] = (short)f2bf(w0[2]); bfr[3] = (short)f2bf(w0[3]);
            bfr[4] = (short)f2bf(w1[0]); bfr[5] = (short)f2bf(w1[1]);
            bfr[6] = (short)f2bf(w1[2]); bfr[7] = (short)f2bf(w1[3]);
            #pragma unroll
            for (int r = 0; r < 4; ++r)
                acc[r][c] = __builtin_amdgcn_mfma_f32_16x16x32_bf16(
                    af[r], bfr, acc[r][c], 0, 0, 0);
        }
        __syncthreads();
    }

    // ---- epilogue: sigmoid gates, combine, scatter ----
    const float bfv0 = bfb[dbase + l15];
    const float bfv1 = bfb[dbase + 16 + l15];
    const float bav0 = bab[dbase + l15];
    const float bav1 = bab[dbase + 16 + l15];

    #pragma unroll
    for (int r = 0; r < 4; ++r) {
        #pragma unroll
        for (int j = 0; j < 4; ++j) {
            const int ml = r * 16 + lk * 4 + j;   // local row (C/D layout)
            const long row = rowbuf[ml];
            const long sym = symbuf[ml];
            const float* pr = flat + row * 256;
            const float* ur = syms + sym * 256;
            float* orow = out + row * 256;
            {
                const int d = dbase + l15;
                float fg = 1.f / (1.f + __expf(-(acc[r][0][j] + bfv0)));
                float ag = 1.f / (1.f + __expf(-(acc[r][2][j] + bav0)));
                orow[d] = fg * pr[d] + ag * ur[d];
            }
            {
                const int d = dbase + 16 + l15;
                float fg = 1.f / (1.f + __expf(-(acc[r][1][j] + bfv1)));
                float ag = 1.f / (1.f + __expf(-(acc[r][3][j] + bav1)));
                orow[d] = fg * pr[d] + ag * ur[d];
            }
        }
    }
}

extern "C" void kernel_launch(void* const* d_in, const int* in_sizes, int n_in,
                              void* d_out, int out_size, void* d_ws, size_t ws_size,
                              hipStream_t stream) {
    const float* flat = (const float*)d_in[0];
    const float* syms = (const float*)d_in[1];
    const float* Wf   = (const float*)d_in[2];
    const float* bf   = (const float*)d_in[3];
    const float* Wa   = (const float*)d_in[4];
    const float* ba   = (const float*)d_in[5];
    const int* ei     = (const int*)d_in[6];
    const int* ti     = (const int*)d_in[7];
    const int* si     = (const int*)d_in[8];
    float* out        = (float*)d_out;

    // 1) out <- flat (rows not updated keep original values)
    hipMemcpyAsync(out, flat, (size_t)out_size * sizeof(float),
                   hipMemcpyDeviceToDevice, stream);

    // 2) fused gather/GEMM/gate/scatter over 131072 occurrences, 64 per block
    const int n_occ = in_sizes[6];
    const int nblk  = n_occ / 64;   // 2048
    gate_gemm_kernel<<<nblk, 512, 0, stream>>>(flat, syms, Wf, bf, Wa, ba,
                                               ei, ti, si, out);
}

// Round 2
// 297.065 us; speedup vs baseline: 1.6349x; 1.6349x over previous
//
#include <hip/hip_runtime.h>

typedef __attribute__((ext_vector_type(8))) short short8;
typedef __attribute__((ext_vector_type(4))) short short4v;
typedef __attribute__((ext_vector_type(4))) float floatx4;

__device__ __forceinline__ unsigned short f2bf(float f) {
    unsigned int u = __float_as_uint(f);
    u += 0x7FFFu + ((u >> 16) & 1u);   // round-to-nearest-even
    return (unsigned short)(u >> 16);
}

// Prologue: convert Wf|Wa (fp32, row-major [256,512] each) into bf16,
// pre-swizzled into MFMA B-fragment order so the GEMM kernel's per-lane
// fragment load is one coalesced short8.
// Layout: short8 index = (g*16 + ks)*64 + lk*16 + l15
//   g in [0,32): 16-column group. g<16 -> Wf rows g*16+l15; g>=16 -> Wa rows.
//   ks in [0,16): K-step of 32;  lane holds k = ks*32 + lk*8 .. +8.
__global__ __launch_bounds__(256)
void convert_w_kernel(const float* __restrict__ Wf,
                      const float* __restrict__ Wa,
                      short* __restrict__ wswz)
{
    int id = blockIdx.x * 256 + threadIdx.x;       // 32768 total
    int slot = id & 63;
    int ks   = (id >> 6) & 15;
    int g    = id >> 10;
    int l15  = slot & 15, lk = slot >> 4;
    const float* base = (g < 16) ? (Wf + (long)(g * 16 + l15) * 512)
                                 : (Wa + (long)((g - 16) * 16 + l15) * 512);
    const float* src = base + ks * 32 + lk * 8;
    floatx4 w0 = *(const floatx4*)src;
    floatx4 w1 = *(const floatx4*)(src + 4);
    short8 o;
    o[0] = (short)f2bf(w0[0]); o[1] = (short)f2bf(w0[1]);
    o[2] = (short)f2bf(w0[2]); o[3] = (short)f2bf(w0[3]);
    o[4] = (short)f2bf(w1[0]); o[5] = (short)f2bf(w1[1]);
    o[6] = (short)f2bf(w1[2]); o[7] = (short)f2bf(w1[3]);
    *(short8*)(wswz + (long)id * 8) = o;
}

// Fused gather + bf16 GEMM (concat[131072,512] @ W[512,512]) + sigmoid gates +
// gated combine + row scatter.
// Block: 512 threads (8 waves), 64 occurrence rows. Whole A-tile (64x512 bf16)
// staged to LDS ONCE (single barrier), then 256 MFMAs/wave barrier-free.
// Wave w computes cols d in [32w,32w+32) for BOTH gates -> wave-local epilogue.
__global__ __launch_bounds__(512, 4)
void gate_gemm_kernel(const float* __restrict__ flat,   // [262144,256]
                      const float* __restrict__ syms,   // [20000,256]
                      const float* __restrict__ bfb,    // [256]
                      const float* __restrict__ bab,    // [256]
                      const int* __restrict__ expr_idx,
                      const int* __restrict__ token_idx,
                      const int* __restrict__ sym_idx,
                      const short* __restrict__ wswz,   // [512,512] bf16 swizzled
                      float* __restrict__ out)          // [262144,256]
{
    __shared__ __align__(16) short A_lds[64][520];  // 64 rows x 512 k, +8 pad
    __shared__ int rowbuf[64];
    __shared__ int symbuf[64];

    const int tid  = threadIdx.x;
    const int occ0 = blockIdx.x * 64;

    if (tid < 64) {
        int occ = occ0 + tid;
        rowbuf[tid] = 64 * expr_idx[occ] + token_idx[occ];
        symbuf[tid] = sym_idx[occ];
    }
    __syncthreads();

    // ---- stage full A tile: fp32 gather -> bf16 LDS, one shot ----
    // thread t: row = t>>3, eighth = t&7; 16 float4 loads cover k=0..511.
    // Lanes 0-7 of each group read 128B contiguous within one row.
    {
        const int srow = tid >> 3;
        const int se   = tid & 7;
        const float* prow = flat + (long)rowbuf[srow] * 256;
        const float* urow = syms + (long)symbuf[srow] * 256;
        #pragma unroll
        for (int it = 0; it < 16; ++it) {
            const int k4 = se + it * 8;          // float4 index, 0..127
            const int k  = k4 * 4;               // 0..508
            const float* s = (k < 256) ? (prow + k) : (urow + (k - 256));
            floatx4 v = *(const floatx4*)s;
            short4v sv;
            sv[0] = (short)f2bf(v[0]); sv[1] = (short)f2bf(v[1]);
            sv[2] = (short)f2bf(v[2]); sv[3] = (short)f2bf(v[3]);
            *(short4v*)&A_lds[srow][k] = sv;
        }
    }
    __syncthreads();

    const int lane  = tid & 63;
    const int wv    = tid >> 6;   // 0..7
    const int l15   = lane & 15;
    const int lk    = lane >> 4;  // 0..3
    const int dbase = wv * 32;

    floatx4 acc[4][4];
    #pragma unroll
    for (int r = 0; r < 4; ++r)
        #pragma unroll
        for (int c = 0; c < 4; ++c)
            acc[r][c] = (floatx4){0.f, 0.f, 0.f, 0.f};

    const short8* wsv = (const short8*)wswz;

    #pragma unroll
    for (int ks = 0; ks < 16; ++ks) {
        short8 af[4];
        #pragma unroll
        for (int r = 0; r < 4; ++r)
            af[r] = *(const short8*)&A_lds[r * 16 + l15][ks * 32 + lk * 8];

        #pragma unroll
        for (int c = 0; c < 4; ++c) {
            const int g = (c < 2) ? (wv * 2 + (c & 1)) : (16 + wv * 2 + (c & 1));
            short8 bfr = wsv[(g * 16 + ks) * 64 + lk * 16 + l15];
            #pragma unroll
            for (int r = 0; r < 4; ++r)
                acc[r][c] = __builtin_amdgcn_mfma_f32_16x16x32_bf16(
                    af[r], bfr, acc[r][c], 0, 0, 0);
        }
    }

    // ---- epilogue: sigmoid gates, combine, scatter ----
    const float bfv0 = bfb[dbase + l15];
    const float bfv1 = bfb[dbase + 16 + l15];
    const float bav0 = bab[dbase + l15];
    const float bav1 = bab[dbase + 16 + l15];

    #pragma unroll
    for (int r = 0; r < 4; ++r) {
        #pragma unroll
        for (int j = 0; j < 4; ++j) {
            const int ml = r * 16 + lk * 4 + j;   // local row (C/D layout)
            const long row = rowbuf[ml];
            const long sym = symbuf[ml];
            const float* pr = flat + row * 256;
            const float* ur = syms + sym * 256;
            float* orow = out + row * 256;
            {
                const int d = dbase + l15;
                float fg = 1.f / (1.f + __expf(-(acc[r][0][j] + bfv0)));
                float ag = 1.f / (1.f + __expf(-(acc[r][2][j] + bav0)));
                orow[d] = fg * pr[d] + ag * ur[d];
            }
            {
                const int d = dbase + 16 + l15;
                float fg = 1.f / (1.f + __expf(-(acc[r][1][j] + bfv1)));
                float ag = 1.f / (1.f + __expf(-(acc[r][3][j] + bav1)));
                orow[d] = fg * pr[d] + ag * ur[d];
            }
        }
    }
}

extern "C" void kernel_launch(void* const* d_in, const int* in_sizes, int n_in,
                              void* d_out, int out_size, void* d_ws, size_t ws_size,
                              hipStream_t stream) {
    const float* flat = (const float*)d_in[0];
    const float* syms = (const float*)d_in[1];
    const float* Wf   = (const float*)d_in[2];
    const float* bf   = (const float*)d_in[3];
    const float* Wa   = (const float*)d_in[4];
    const float* ba   = (const float*)d_in[5];
    const int* ei     = (const int*)d_in[6];
    const int* ti     = (const int*)d_in[7];
    const int* si     = (const int*)d_in[8];
    float* out        = (float*)d_out;
    short* wswz       = (short*)d_ws;   // needs 512 KB

    // 1) weights fp32 -> bf16, fragment-swizzled (one-time, ~1 MB read)
    convert_w_kernel<<<128, 256, 0, stream>>>(Wf, Wa, wswz);

    // 2) out <- flat (rows not updated keep original values)
    hipMemcpyAsync(out, flat, (size_t)out_size * sizeof(float),
                   hipMemcpyDeviceToDevice, stream);

    // 3) fused gather/GEMM/gate/scatter, 64 occurrences per block
    const int n_occ = in_sizes[6];
    const int nblk  = n_occ / 64;   // 2048
    gate_gemm_kernel<<<nblk, 512, 0, stream>>>(flat, syms, bf, ba,
                                               ei, ti, si, wswz, out);
}

// Round 3
// 229.422 us; speedup vs baseline: 2.1170x; 1.2948x over previous
//
#include <hip/hip_runtime.h>

typedef __attribute__((ext_vector_type(8))) short short8;
typedef __attribute__((ext_vector_type(4))) short short4v;
typedef __attribute__((ext_vector_type(4))) float floatx4;

__device__ __forceinline__ unsigned short f2bf(float f) {
    unsigned int u = __float_as_uint(f);
    u += 0x7FFFu + ((u >> 16) & 1u);   // round-to-nearest-even
    return (unsigned short)(u >> 16);
}
__device__ __forceinline__ float bf2f(unsigned short s) {
    return __uint_as_float(((unsigned int)s) << 16);
}

// Prologue: Wf|Wa fp32 [256,512] -> bf16, MFMA-B-fragment order.
// short8 index = (g*16 + ks)*64 + lk*16 + l15
//   g in [0,32): 16-col group (g<16 -> Wf row g*16+l15, else Wa);
//   lane holds k = ks*32 + lk*8 .. +8.
__global__ __launch_bounds__(256)
void convert_w_kernel(const float* __restrict__ Wf,
                      const float* __restrict__ Wa,
                      short* __restrict__ wswz)
{
    int id = blockIdx.x * 256 + threadIdx.x;       // 32768 total
    int slot = id & 63;
    int ks   = (id >> 6) & 15;
    int g    = id >> 10;
    int l15  = slot & 15, lk = slot >> 4;
    const float* base = (g < 16) ? (Wf + (long)(g * 16 + l15) * 512)
                                 : (Wa + (long)((g - 16) * 16 + l15) * 512);
    const float* src = base + ks * 32 + lk * 8;
    floatx4 w0 = *(const floatx4*)src;
    floatx4 w1 = *(const floatx4*)(src + 4);
    short8 o;
    o[0] = (short)f2bf(w0[0]); o[1] = (short)f2bf(w0[1]);
    o[2] = (short)f2bf(w0[2]); o[3] = (short)f2bf(w0[3]);
    o[4] = (short)f2bf(w1[0]); o[5] = (short)f2bf(w1[1]);
    o[6] = (short)f2bf(w1[2]); o[7] = (short)f2bf(w1[3]);
    *(short8*)(wswz + (long)id * 8) = o;
}

// Mark updated rows.
__global__ __launch_bounds__(256)
void mark_kernel(const int* __restrict__ ei, const int* __restrict__ ti,
                 unsigned char* __restrict__ flags, int n)
{
    int i = blockIdx.x * 256 + threadIdx.x;
    if (i < n) flags[64 * ei[i] + ti[i]] = 1;
}

// Copy rows NOT updated by the scatter. One wave per row (float4/lane covers
// 256 floats exactly); flag branch is wave-uniform.
__global__ __launch_bounds__(256)
void copy_rest_kernel(const float* __restrict__ flat,
                      const unsigned char* __restrict__ flags,
                      float* __restrict__ out, int nrows)
{
    const int lane = threadIdx.x & 63;
    const int w0   = (blockIdx.x * 256 + threadIdx.x) >> 6;
    const int nw   = (gridDim.x * 256) >> 6;
    for (int row = w0; row < nrows; row += nw) {
        if (flags[row]) continue;
        const floatx4* s = (const floatx4*)(flat + (long)row * 256);
        floatx4*       o = (floatx4*)(out + (long)row * 256);
        o[lane] = s[lane];
    }
}

// Fused gather + bf16 GEMM + sigmoid gates + gated combine + row scatter.
// Block: 256 threads (4 waves), BM=32 occurrence rows, LDS 33 KB -> 4 blk/CU.
// Wave w owns cols [64w, 64w+64) for BOTH gates (acc[2][8]).
// Epilogue reuses bf16 prev/upd from A_lds (no global re-reads).
__global__ __launch_bounds__(256, 4)
void gate_gemm_kernel(const float* __restrict__ flat,   // [262144,256]
                      const float* __restrict__ syms,   // [20000,256]
                      const float* __restrict__ bfb,    // [256]
                      const float* __restrict__ bab,    // [256]
                      const int* __restrict__ expr_idx,
                      const int* __restrict__ token_idx,
                      const int* __restrict__ sym_idx,
                      const short* __restrict__ wswz,   // bf16 swizzled weights
                      float* __restrict__ out)          // [262144,256]
{
    __shared__ __align__(16) short A_lds[32][520];  // 32 rows x 512 k, +8 pad
    __shared__ int rowbuf[32];
    __shared__ int symbuf[32];

    const int tid  = threadIdx.x;
    const int occ0 = blockIdx.x * 32;

    if (tid < 32) {
        int occ = occ0 + tid;
        rowbuf[tid] = 64 * expr_idx[occ] + token_idx[occ];
        symbuf[tid] = sym_idx[occ];
    }
    __syncthreads();

    // ---- stage full A tile: 16 threads/row (conflict-free ds_write_b64,
    // 256B contiguous read segments per row) ----
    {
        const int srow0 = tid >> 4;    // 0..15
        const int se    = tid & 15;
        #pragma unroll
        for (int half = 0; half < 2; ++half) {
            const int srow = srow0 + half * 16;
            const float* prow = flat + (long)rowbuf[srow] * 256;
            const float* urow = syms + (long)symbuf[srow] * 256;
            #pragma unroll
            for (int it = 0; it < 4; ++it) {
                const int k = (se + it * 16) * 4;          // 0..252*... covers 0..255
                floatx4 v = *(const floatx4*)(prow + k);
                short4v sv;
                sv[0] = (short)f2bf(v[0]); sv[1] = (short)f2bf(v[1]);
                sv[2] = (short)f2bf(v[2]); sv[3] = (short)f2bf(v[3]);
                *(short4v*)&A_lds[srow][k] = sv;
            }
            #pragma unroll
            for (int it = 0; it < 4; ++it) {
                const int k = (se + it * 16) * 4;
                floatx4 v = *(const floatx4*)(urow + k);
                short4v sv;
                sv[0] = (short)f2bf(v[0]); sv[1] = (short)f2bf(v[1]);
                sv[2] = (short)f2bf(v[2]); sv[3] = (short)f2bf(v[3]);
                *(short4v*)&A_lds[srow][256 + k] = sv;
            }
        }
    }
    __syncthreads();

    const int lane  = tid & 63;
    const int wv    = tid >> 6;   // 0..3
    const int l15   = lane & 15;
    const int lk    = lane >> 4;  // 0..3
    const int dbase = wv * 64;

    floatx4 acc[2][8];
    #pragma unroll
    for (int r = 0; r < 2; ++r)
        #pragma unroll
        for (int c = 0; c < 8; ++c)
            acc[r][c] = (floatx4){0.f, 0.f, 0.f, 0.f};

    const short8* wsv = (const short8*)wswz;

    #pragma unroll
    for (int ks = 0; ks < 16; ++ks) {
        short8 af0 = *(const short8*)&A_lds[l15][ks * 32 + lk * 8];
        short8 af1 = *(const short8*)&A_lds[16 + l15][ks * 32 + lk * 8];
        #pragma unroll
        for (int c = 0; c < 8; ++c) {
            const int g = (c < 4) ? (wv * 4 + c) : (16 + wv * 4 + (c - 4));
            short8 bfr = wsv[(g * 16 + ks) * 64 + lk * 16 + l15];
            acc[0][c] = __builtin_amdgcn_mfma_f32_16x16x32_bf16(af0, bfr, acc[0][c], 0, 0, 0);
            acc[1][c] = __builtin_amdgcn_mfma_f32_16x16x32_bf16(af1, bfr, acc[1][c], 0, 0, 0);
        }
    }

    // ---- epilogue: gates from acc, prev/upd from LDS (bf16), scatter ----
    float bfv[4], bav[4];
    #pragma unroll
    for (int cf = 0; cf < 4; ++cf) {
        const int d = dbase + cf * 16 + l15;
        bfv[cf] = bfb[d];
        bav[cf] = bab[d];
    }

    #pragma unroll
    for (int r = 0; r < 2; ++r) {
        #pragma unroll
        for (int j = 0; j < 4; ++j) {
            const int ml = r * 16 + lk * 4 + j;   // local row (C/D layout)
            float* orow = out + (long)rowbuf[ml] * 256;
            #pragma unroll
            for (int cf = 0; cf < 4; ++cf) {
                const int d = dbase + cf * 16 + l15;
                float prev = bf2f((unsigned short)A_lds[ml][d]);
                float upd  = bf2f((unsigned short)A_lds[ml][256 + d]);
                float fg = 1.f / (1.f + __expf(-(acc[r][cf][j]     + bfv[cf])));
                float ag = 1.f / (1.f + __expf(-(acc[r][4 + cf][j] + bav[cf])));
                orow[d] = fg * prev + ag * upd;
            }
        }
    }
}

extern "C" void kernel_launch(void* const* d_in, const int* in_sizes, int n_in,
                              void* d_out, int out_size, void* d_ws, size_t ws_size,
                              hipStream_t stream) {
    const float* flat = (const float*)d_in[0];
    const float* syms = (const float*)d_in[1];
    const float* Wf   = (const float*)d_in[2];
    const float* bf   = (const float*)d_in[3];
    const float* Wa   = (const float*)d_in[4];
    const float* ba   = (const float*)d_in[5];
    const int* ei     = (const int*)d_in[6];
    const int* ti     = (const int*)d_in[7];
    const int* si     = (const int*)d_in[8];
    float* out        = (float*)d_out;

    short* wswz          = (short*)d_ws;                        // 512 KB
    unsigned char* flags = (unsigned char*)d_ws + 512 * 1024;   // 256 KB

    const int n_occ = in_sizes[6];        // 131072
    const int nrows = out_size / 256;     // 262144

    // flags <- 0 (d_ws is poisoned; must rebuild every call), then mark
    hipMemsetAsync(flags, 0, nrows, stream);
    mark_kernel<<<(n_occ + 255) / 256, 256, 0, stream>>>(ei, ti, flags, n_occ);

    // weights fp32 -> bf16 fragment-swizzled
    convert_w_kernel<<<128, 256, 0, stream>>>(Wf, Wa, wswz);

    // fused gather/GEMM/gate/scatter: 32 occurrences per block
    gate_gemm_kernel<<<n_occ / 32, 256, 0, stream>>>(flat, syms, bf, ba,
                                                     ei, ti, si, wswz, out);

    // copy the non-updated rows
    copy_rest_kernel<<<2048, 256, 0, stream>>>(flat, flags, out, nrows);
}